// Round 1
// baseline (117.917 us; speedup 1.0000x reference)
//
#include <hip/hip_runtime.h>
#include <hip/hip_bf16.h>

// Problem constants (fixed by the reference)
#define NB   8
#define C    128
#define H    112
#define W    112
#define HO   56
#define WO   56
#define KK   9      // 3x3 = 9 sigma channels
#define WAVES 16
#define CPW  8      // channels per wave = C / WAVES
#define WT_ELEMS (C * 3 * 27)   // wt[ci][kh][k*3+kw], BN-scale folded in

// Module-level scratch (avoids reliance on ws_size); rewritten every launch.
__device__ float g_wt[WT_ELEMS];
__device__ float g_shift[KK];

// ---------------------------------------------------------------------------
// Kernel 0: transpose conv weights to [ci][kh][k*3+kw] and fold in BN scale.
// Also compute per-k shift. 10368 + 9 elements total.
// ---------------------------------------------------------------------------
__global__ void pasa_prep(const float* __restrict__ cw,
                          const float* __restrict__ bw,
                          const float* __restrict__ bb,
                          const float* __restrict__ bm,
                          const float* __restrict__ bv) {
    int idx = blockIdx.x * 256 + threadIdx.x;
    if (idx < WT_ELEMS) {
        int ci = idx / 81;
        int rem = idx % 81;
        int kh = rem / 27;
        int r2 = rem % 27;
        int k  = r2 / 3;
        int kw = r2 % 3;
        float scale = bw[k] / sqrtf(bv[k] + 1e-5f);
        g_wt[idx] = cw[((k * C + ci) * 3 + kh) * 3 + kw] * scale;
    } else if (idx < WT_ELEMS + KK) {
        int k = idx - WT_ELEMS;
        float scale = bw[k] / sqrtf(bv[k] + 1e-5f);
        g_shift[k] = bb[k] - bm[k] * scale;
    }
}

// ---------------------------------------------------------------------------
// Kernel 1: fused PASA downsample. One block per (n, ho) output row.
// 16 waves; lane = wo (56 active of 64). Phase A: sigma conv (each wave
// reduces 8 channels, cross-wave reduce in LDS). Phase B: adaptive filter
// apply + stride-2 store.
// ---------------------------------------------------------------------------
__global__ __launch_bounds__(1024)
void pasa_main(const float* __restrict__ x, float* __restrict__ out) {
    __shared__ float part[WAVES * KK * 64];   // 36 KB
    __shared__ float sig[KK * 57];            // padded row stride

    const int bid  = blockIdx.x;
    const int n    = bid / HO;
    const int ho   = bid % HO;
    const int tid  = threadIdx.x;
    const int lane = tid & 63;
    const int wv   = __builtin_amdgcn_readfirstlane(tid >> 6);  // force wave-uniform
    const int wo   = lane < WO ? lane : (WO - 1);               // clamp inactive lanes

    // Reflection-resolved source rows for taps kh=0,1,2 (top reflect only:
    // y = 2*ho in [0,110], so y+kh-1 in [-1,111]; -1 reflects to 1).
    int rows[3];
    rows[0] = (ho == 0) ? 1 : (2 * ho - 1);
    rows[1] = 2 * ho;
    rows[2] = 2 * ho + 1;

    const float* xn = x + (size_t)n * C * H * W;

    // ---- Phase A: partial sigma over this wave's channels -----------------
    float acc[KK];
#pragma unroll
    for (int k = 0; k < KK; ++k) acc[k] = 0.0f;

    for (int i = 0; i < CPW; ++i) {
        const int ci = wv * CPW + i;                       // wave-uniform
        const float* xc = xn + (size_t)ci * (H * W);
        const float* wb = g_wt + ci * 81;                  // uniform -> s_load
#pragma unroll
        for (int kh = 0; kh < 3; ++kh) {
            const float2 v = *(const float2*)(xc + rows[kh] * W + 2 * wo);
            const float t1 = v.x;
            const float t2 = v.y;
            // col 2wo-1: previous lane's t2; lane 0 keeps own t2 = row[1],
            // which is exactly the reflect(-1)=1 value.
            const float t0 = __shfl_up(t2, 1);
            const float* wr = wb + kh * 27;                // uniform
#pragma unroll
            for (int k = 0; k < KK; ++k) {
                acc[k] = fmaf(t2, wr[3 * k + 2],
                         fmaf(t1, wr[3 * k + 1],
                         fmaf(t0, wr[3 * k + 0], acc[k])));
            }
        }
    }

#pragma unroll
    for (int k = 0; k < KK; ++k) part[(wv * KK + k) * 64 + lane] = acc[k];
    __syncthreads();

    // ---- Cross-wave reduce + BN shift + clamp -----------------------------
    if (tid < KK * WO) {
        const int k = tid / WO;
        const int w_ = tid % WO;
        float s = 0.0f;
#pragma unroll
        for (int w2 = 0; w2 < WAVES; ++w2) s += part[(w2 * KK + k) * 64 + w_];
        s += g_shift[k];
        s = fmaxf(s, 1e-4f);
        sig[k * 57 + w_] = s;
    }
    __syncthreads();

    // ---- Normalize into registers (per-lane, lane = wo) -------------------
    float sg[KK];
    float tot = 0.0f;
#pragma unroll
    for (int k = 0; k < KK; ++k) { sg[k] = sig[k * 57 + wo]; tot += sg[k]; }
    const float inv = 1.0f / tot;
#pragma unroll
    for (int k = 0; k < KK; ++k) sg[k] *= inv;

    // ---- Phase B: apply adaptive filter at stride-2 positions -------------
    float* on = out + ((size_t)n * C) * (HO * WO) + ho * WO;
    for (int i = 0; i < CPW; ++i) {
        const int ci = wv * CPW + i;
        const float* xc = xn + (size_t)ci * (H * W);
        float o = 0.0f;
#pragma unroll
        for (int kh = 0; kh < 3; ++kh) {
            const float2 v = *(const float2*)(xc + rows[kh] * W + 2 * wo);
            const float t1 = v.x;
            const float t2 = v.y;
            const float t0 = __shfl_up(t2, 1);
            o = fmaf(t0, sg[kh * 3 + 0],
                fmaf(t1, sg[kh * 3 + 1],
                fmaf(t2, sg[kh * 3 + 2], o)));
        }
        if (lane < WO) on[(size_t)ci * (HO * WO) + lane] = o;
    }
}

extern "C" void kernel_launch(void* const* d_in, const int* in_sizes, int n_in,
                              void* d_out, int out_size, void* d_ws, size_t ws_size,
                              hipStream_t stream) {
    const float* x   = (const float*)d_in[0];
    const float* cw  = (const float*)d_in[1];
    const float* bw  = (const float*)d_in[2];
    const float* bb  = (const float*)d_in[3];
    const float* bm  = (const float*)d_in[4];
    const float* bv  = (const float*)d_in[5];
    float* out = (float*)d_out;

    const int prep_elems = WT_ELEMS + KK;
    pasa_prep<<<(prep_elems + 255) / 256, 256, 0, stream>>>(cw, bw, bb, bm, bv);
    pasa_main<<<NB * HO, 1024, 0, stream>>>(x, out);
}